// Round 8
// baseline (2272.076 us; speedup 1.0000x reference)
//
#include <hip/hip_runtime.h>
#include <hip/hip_bf16.h>

#define TSTEPS 256
#define NBLK 256

typedef short bf16x8 __attribute__((ext_vector_type(8)));
typedef float f32x4 __attribute__((ext_vector_type(4)));
typedef unsigned u32x2 __attribute__((ext_vector_type(2)));

__device__ __forceinline__ unsigned short f2bf(float f) {
    union { float f; unsigned u; } v; v.f = f;
    unsigned r = v.u + 0x7FFFu + ((v.u >> 16) & 1u);
    return (unsigned short)(r >> 16);
}
__device__ __forceinline__ float bf2f(unsigned short s) {
    union { unsigned u; float f; } v; v.u = ((unsigned)s) << 16; return v.f;
}

__global__ void hq_marker(float* out) { out[0] = 12345.0f; }

// W2 [4][1024 k][1024 h] f32  ->  W2T [4][1024 h][1024 k] bf16
__global__ void hq_transpose(const float* __restrict__ in, unsigned short* __restrict__ out) {
    __shared__ float tile[64][65];
    const int R = 1024, C = 1024;
    int r0 = blockIdx.y * 64, c0 = blockIdx.x * 64;
    const float* src = in + (long)blockIdx.z * R * C;
    unsigned short* dst = out + (long)blockIdx.z * R * C;
    int col = threadIdx.x & 63, rr = threadIdx.x >> 6;
#pragma unroll
    for (int i = 0; i < 16; ++i) {
        int row = rr + i * 4;
        tile[row][col] = src[(long)(r0 + row) * C + c0 + col];
    }
    __syncthreads();
#pragma unroll
    for (int i = 0; i < 16; ++i) {
        int row = rr + i * 4;
        dst[(long)(c0 + row) * R + r0 + col] = f2bf(tile[col][row]);
    }
}

// beff[g][h] = sum_k b1[g][k]*W2[g][k][h] + b2[g][h]
__global__ void hq_beff(const unsigned short* __restrict__ w2t, const float* __restrict__ b1,
                        const float* __restrict__ b2, float* __restrict__ beff) {
    int g = blockIdx.y;
    int h = blockIdx.x * 256 + threadIdx.x;
    const unsigned short* row = w2t + ((long)(g * 1024 + h)) * 1024;
    float s = 0.f;
    for (int k = 0; k < 1024; k += 8) {
        bf16x8 v = *reinterpret_cast<const bf16x8*>(row + k);
#pragma unroll
        for (int j = 0; j < 8; ++j) s += bf2f((unsigned short)v[j]) * b1[g * 1024 + k + j];
    }
    beff[g * 1024 + h] = s + b2[g * 1024 + h];
}

// WeffT[g][h][d] = sum_k W2T[g][h][k] * W1[g][d][k]
__global__ void hq_weff(const unsigned short* __restrict__ w2t, const float* __restrict__ w1,
                        unsigned short* __restrict__ wefft) {
    __shared__ unsigned short atile[64][136];
    const int g = blockIdx.z;
    const int d0 = blockIdx.x * 64;
    const int h0 = blockIdx.y * 64;
    const int tid = threadIdx.x;
    const int w = tid >> 6, lane = tid & 63;
    const int fr = lane & 15, fq = lane >> 4;
    f32x4 acc[4] = {};
    const int drow = d0 + w * 16 + fr;
    const float* bsrc = w1 + ((long)g * 2048 + drow) * 1024;
    for (int kc = 0; kc < 8; ++kc) {
#pragma unroll
        for (int i = 0; i < 4; ++i) {
            int id = tid + i * 256;
            int row = id >> 4, c8 = id & 15;
            bf16x8 v = *reinterpret_cast<const bf16x8*>(
                w2t + ((long)(g * 1024 + h0 + row)) * 1024 + kc * 128 + c8 * 8);
            *reinterpret_cast<bf16x8*>(&atile[row][c8 * 8]) = v;
        }
        __syncthreads();
#pragma unroll
        for (int kk = 0; kk < 4; ++kk) {
            int kl = kk * 32 + fq * 8;
            int kg = kc * 128 + kl;
            float4 bA = *reinterpret_cast<const float4*>(bsrc + kg);
            float4 bB = *reinterpret_cast<const float4*>(bsrc + kg + 4);
            bf16x8 bfv;
            bfv[0] = (short)f2bf(bA.x); bfv[1] = (short)f2bf(bA.y);
            bfv[2] = (short)f2bf(bA.z); bfv[3] = (short)f2bf(bA.w);
            bfv[4] = (short)f2bf(bB.x); bfv[5] = (short)f2bf(bB.y);
            bfv[6] = (short)f2bf(bB.z); bfv[7] = (short)f2bf(bB.w);
#pragma unroll
            for (int mi = 0; mi < 4; ++mi) {
                bf16x8 af = *reinterpret_cast<const bf16x8*>(&atile[mi * 16 + fr][kl]);
                acc[mi] = __builtin_amdgcn_mfma_f32_16x16x32_bf16(af, bfv, acc[mi], 0, 0, 0);
            }
        }
        __syncthreads();
    }
#pragma unroll
    for (int mi = 0; mi < 4; ++mi)
#pragma unroll
        for (int r = 0; r < 4; ++r) {
            int h = h0 + mi * 16 + fq * 4 + r;
            int d = d0 + w * 16 + fr;
            wefft[((long)(g * 1024 + h)) * 2048 + d] = f2bf(acc[mi][r]);
        }
}

// inputs f32 -> bf16
__global__ void hq_xconv(const float* __restrict__ x, unsigned short* __restrict__ xbf) {
    long i = (long)blockIdx.x * 256 + threadIdx.x;
    for (; i < 4194304L; i += 524288L) {
        float4 v = reinterpret_cast<const float4*>(x)[i];
        ushort4 o;
        o.x = f2bf(v.x); o.y = f2bf(v.y); o.z = f2bf(v.z); o.w = f2bf(v.w);
        reinterpret_cast<ushort4*>(xbf)[i] = o;
    }
}

// Coherent 8B flag read (MALL-direct; flags must never be cached)
__device__ __forceinline__ u32x2 coh_load_flags(const unsigned* p) {
    u32x2 r;
    asm volatile(
        "global_load_dwordx2 %0, %[a], off sc0 sc1\n\t"
        "s_waitcnt vmcnt(0)"
        : "=&v"(r) : [a] "v"(p) : "memory");
    return r;
}
__device__ __forceinline__ void vm_drain() {
    asm volatile("s_waitcnt vmcnt(0)" ::: "memory");
}

// Persistent sequential kernel, fence-free-publish + acquire-fence-consume barrier.
// grid 256 = (bq 2) x (cb 128); block 1024 = 16 waves, wave kq owns 128 K-slice.
// Wave roles: kq0-7 x-load+MFMA; kq0-3 also epilogue (gates + hx MALL store + publish).
// kq8 polls 128 same-bq flags (MALL-direct), then issues ONE acquire-agent fence
// (invalidates this CU's L1 + this XCD's L2), then release-relays via LDS; kq8-15
// then read hx with PLAIN CACHED loads -> first block per XCD fills L2, rest L2-hit.
// kq12-15 do the outs/hxf/cxf HBM stores via LDS handoff (off the publish chain).
__global__ __launch_bounds__(1024, 4) void hq_seq(
    const unsigned short* __restrict__ xbf,     // [256][64][1024] bf16
    const unsigned short* __restrict__ wefft,   // [4][1024][2048] bf16
    const float* __restrict__ beff,             // [4][1024]
    float* __restrict__ outs,                   // [256][64][1024] f32
    float* __restrict__ hxf, float* __restrict__ cxf,
    unsigned short* __restrict__ hxbuf,         // [2][64][1024] bf16 (no init needed)
    unsigned* __restrict__ flags)               // [256] zeroed per launch
{
    __shared__ float zpart[16][2][32][16];      // 64 KB, row XOR-swizzled
    __shared__ float hvbuf[256];                // hv handoff epilogue -> waves 12-15
    __shared__ float cbuf[256];                 // creg handoff (final step only)
    __shared__ unsigned ready;
    const int tid = threadIdx.x;
    const int lane = tid & 63, kq = tid >> 6;
    const int fr = lane & 15, fq = lane >> 4;
    const int bid = blockIdx.x;
    const int bq = bid >> 7, cb = bid & 127;
    const int b0 = bq * 32, ho = cb * 8;
    const int k0 = kq * 128;

    if (tid == 0) ready = 0;

    // ---- preload B fragments: [nt 2][ks 4] = 32 regs/lane ----
    bf16x8 breg[2][4];
#pragma unroll
    for (int nt = 0; nt < 2; ++nt) {
        const int col = nt * 16 + fr;
        const int g = col >> 3, hl = col & 7;
        const unsigned short* wrow = wefft + ((long)(g * 1024 + ho + hl)) * 2048 + k0 + fq * 8;
#pragma unroll
        for (int s = 0; s < 4; ++s) breg[nt][s] = *(const bf16x8*)(wrow + s * 32);
    }

    const int eb = tid >> 3, ehl = tid & 7;
    float creg = 0.f;
    float be[4] = {0.f, 0.f, 0.f, 0.f};
    if (tid < 256) {
#pragma unroll
        for (int g = 0; g < 4; ++g) be[g] = beff[g * 1024 + ho + ehl];
    }
    __syncthreads();                              // ready init visible

    for (int t = 0; t < TSTEPS; ++t) {
        bf16x8 af[8];                             // [mt*4 + s]
        if (kq < 8) {
            const unsigned short* p0 = xbf + ((long)(t * 64 + b0 + fr)) * 1024 + k0 + fq * 8;
            const unsigned short* p1 = p0 + 16 * 1024;
#pragma unroll
            for (int s = 0; s < 4; ++s) {
                af[s]     = *(const bf16x8*)(p0 + s * 32);
                af[4 + s] = *(const bf16x8*)(p1 + s * 32);
            }
        } else if (t == 0) {
#pragma unroll
            for (int i = 0; i < 8; ++i) af[i] = (bf16x8){0, 0, 0, 0, 0, 0, 0, 0};
        } else {
            if (kq == 8) {
                const unsigned* fp = flags + bq * 128 + lane * 2;
                for (int g = 0; g < (1 << 16); ++g) {
                    u32x2 v = coh_load_flags(fp);
                    unsigned m = v.x < v.y ? v.x : v.y;
                    if (__all(m >= (unsigned)t)) break;
                }
                // Invalidate this CU's L1 + this XCD's L2: subsequent plain loads
                // of hx refetch fresh lines from MALL (producers drained pre-flag).
                __builtin_amdgcn_fence(__ATOMIC_ACQUIRE, "agent");
                if (lane == 0)
                    __hip_atomic_store(&ready, (unsigned)t, __ATOMIC_RELEASE,
                                       __HIP_MEMORY_SCOPE_WORKGROUP);
            }
            int guard = 0;
            while (__hip_atomic_load(&ready, __ATOMIC_ACQUIRE,
                                     __HIP_MEMORY_SCOPE_WORKGROUP) < (unsigned)t) {
                __builtin_amdgcn_s_sleep(1);
                if (++guard > (1 << 20)) break;
            }
            // plain cached loads: L2-hit for all but the first toucher per XCD
            const unsigned short* hx_r = hxbuf + (t & 1) * 65536;
            const bf16x8* q0 = (const bf16x8*)(hx_r + ((long)(b0 + fr)) * 1024 + (k0 - 1024) + fq * 8);
            const bf16x8* q1 = q0 + 2048;         // +16 rows * 1024 shorts = 2048 bf16x8
#pragma unroll
            for (int s = 0; s < 4; ++s) {
                af[s]     = q0[s * 4];            // s*32 shorts = s*4 bf16x8
                af[4 + s] = q1[s * 4];
            }
        }

        f32x4 acc[2][2] = {};
#pragma unroll
        for (int s = 0; s < 4; ++s)
#pragma unroll
            for (int mt = 0; mt < 2; ++mt)
#pragma unroll
                for (int nt = 0; nt < 2; ++nt)
                    acc[mt][nt] = __builtin_amdgcn_mfma_f32_16x16x32_bf16(
                        af[mt * 4 + s], breg[nt][s], acc[mt][nt], 0, 0, 0);

#pragma unroll
        for (int mt = 0; mt < 2; ++mt)
#pragma unroll
            for (int nt = 0; nt < 2; ++nt) {
                const int col = nt * 16 + fr;
                const int prow = (fq * 4) ^ ((col & 3) << 2);
                *(f32x4*)&zpart[kq][mt][col][prow] = acc[mt][nt];
            }
        __syncthreads();                          // #1: zpart ready

        if (tid < 256) {
            const int emt = eb >> 4, erow = eb & 15;
            float z[4];
#pragma unroll
            for (int g = 0; g < 4; ++g) {
                const int col = g * 8 + ehl;
                const int pr = erow ^ ((col & 3) << 2);
                float s = be[g];
#pragma unroll
                for (int q = 0; q < 16; ++q) s += zpart[q][emt][col][pr];
                z[g] = s;
            }
            float fg = 1.f / (1.f + __expf(-z[0]));
            float ig = 1.f / (1.f + __expf(-z[1]));
            float gg = 2.f / (1.f + __expf(-2.f * z[2])) - 1.f;
            float og = 1.f / (1.f + __expf(-z[3]));
            creg = fg * creg + ig * gg;
            float hv = og * (2.f / (1.f + __expf(-2.f * creg)) - 1.f);
            const int b = b0 + eb, h = ho + ehl;
            hvbuf[tid] = hv;
            if (t == TSTEPS - 1) cbuf[tid] = creg;

            // hx write-through: pack even/odd h pair into one u32 agent store
            unsigned hb = (unsigned)f2bf(hv);
            unsigned ob = (unsigned)__shfl_xor((int)hb, 1);
            if ((tid & 1) == 0) {
                unsigned pack = (hb & 0xFFFFu) | (ob << 16);
                unsigned* hx_w = (unsigned*)(hxbuf + ((t + 1) & 1) * 65536 + b * 1024 + h);
                __hip_atomic_store(hx_w, pack, __ATOMIC_RELAXED, __HIP_MEMORY_SCOPE_AGENT);
            }
            vm_drain();                           // waits ONLY the hx MALL stores
        }
        __syncthreads();                          // #2: hx drained + hvbuf visible
        if (tid == 0)
            __hip_atomic_store(flags + bid, (unsigned)(t + 1), __ATOMIC_RELAXED,
                               __HIP_MEMORY_SCOPE_AGENT);
        // HBM stores by waves 12-15 (ack absorbed by next-step ready-spin slack)
        if (tid >= 768) {
            const int et = tid - 768;
            const int b = b0 + (et >> 3), h = ho + (et & 7);
            float hv = hvbuf[et];
            outs[((long)(t * 64 + b)) * 1024 + h] = hv;
            if (t == TSTEPS - 1) { hxf[b * 1024 + h] = hv; cxf[b * 1024 + h] = cbuf[et]; }
        }
    }
}

extern "C" void kernel_launch(void* const* d_in, const int* in_sizes, int n_in,
                              void* d_out, int out_size, void* d_ws, size_t ws_size,
                              hipStream_t stream) {
    (void)in_sizes; (void)n_in; (void)out_size;
    const float* x  = (const float*)d_in[0];
    const float* W1 = (const float*)d_in[1];
    const float* b1 = (const float*)d_in[2];
    const float* W2 = (const float*)d_in[3];
    const float* b2 = (const float*)d_in[4];
    float* outs = (float*)d_out;
    float* hxf = outs + 16777216L;
    float* cxf = hxf + 65536;

    // ws layout (bytes)
    const size_t off_wefft = 0;          // 16,777,216  WeffT bf16 [4][1024][2048]
    const size_t off_xbf   = 16777216;   // 33,554,432  xbf bf16 (w2t aliased at head)
    const size_t off_w2t   = off_xbf;    //  8,388,608  consumed before xconv overwrites
    const size_t off_hx    = 50331648;   //    262,144  hx ping-pong [2][64][1024] bf16
    const size_t off_beff  = 50593792;   //     16,384
    const size_t off_flags = 50610176;   //      1,024  flags[256]
    const size_t need      = 50611200;
    if (ws_size < need) { hq_marker<<<1, 1, 0, stream>>>((float*)d_out); return; }

    char* ws = (char*)d_ws;
    unsigned short* wefft = (unsigned short*)(ws + off_wefft);
    unsigned short* xbf   = (unsigned short*)(ws + off_xbf);
    unsigned short* w2t   = (unsigned short*)(ws + off_w2t);
    unsigned short* hxbuf = (unsigned short*)(ws + off_hx);
    float* beff = (float*)(ws + off_beff);
    unsigned* flags = (unsigned*)(ws + off_flags);

    hipMemsetAsync(ws + off_flags, 0, 1024, stream);   // flags = 0 (every replay)
    hq_transpose<<<dim3(16, 16, 4), 256, 0, stream>>>(W2, w2t);
    hq_beff<<<dim3(4, 4), 256, 0, stream>>>(w2t, b1, b2, beff);
    hq_weff<<<dim3(32, 16, 4), 256, 0, stream>>>(w2t, W1, wefft);
    hq_xconv<<<2048, 256, 0, stream>>>(x, xbf);

    const unsigned short* xbf_c = xbf;
    const unsigned short* wefft_c = wefft;
    const float* beff_c = beff;
    void* args[] = { (void*)&xbf_c, (void*)&wefft_c, (void*)&beff_c,
                     (void*)&outs, (void*)&hxf, (void*)&cxf,
                     (void*)&hxbuf, (void*)&flags };
    hipError_t ce = hipLaunchCooperativeKernel((const void*)hq_seq, dim3(NBLK), dim3(1024),
                                               args, 0, stream);
    if (ce != hipSuccess) {
        // 1 block/CU by resource limits; 256 blocks <= 256 CUs -> co-resident anyway
        hq_seq<<<NBLK, 1024, 0, stream>>>(xbf, wefft, beff, outs, hxf, cxf, hxbuf, flags);
    }
}

// Round 9
// 1482.168 us; speedup vs baseline: 1.5329x; 1.5329x over previous
//
#include <hip/hip_runtime.h>
#include <hip/hip_bf16.h>

#define TSTEPS 256
#define NBLK 256

typedef short bf16x8 __attribute__((ext_vector_type(8)));
typedef float f32x4 __attribute__((ext_vector_type(4)));

__device__ __forceinline__ unsigned short f2bf(float f) {
    union { float f; unsigned u; } v; v.f = f;
    unsigned r = v.u + 0x7FFFu + ((v.u >> 16) & 1u);
    return (unsigned short)(r >> 16);
}
__device__ __forceinline__ float bf2f(unsigned short s) {
    union { unsigned u; float f; } v; v.u = ((unsigned)s) << 16; return v.f;
}

__global__ void hq_marker(float* out) { out[0] = 12345.0f; }

// W2 [4][1024 k][1024 h] f32  ->  W2T [4][1024 h][1024 k] bf16
__global__ void hq_transpose(const float* __restrict__ in, unsigned short* __restrict__ out) {
    __shared__ float tile[64][65];
    const int R = 1024, C = 1024;
    int r0 = blockIdx.y * 64, c0 = blockIdx.x * 64;
    const float* src = in + (long)blockIdx.z * R * C;
    unsigned short* dst = out + (long)blockIdx.z * R * C;
    int col = threadIdx.x & 63, rr = threadIdx.x >> 6;
#pragma unroll
    for (int i = 0; i < 16; ++i) {
        int row = rr + i * 4;
        tile[row][col] = src[(long)(r0 + row) * C + c0 + col];
    }
    __syncthreads();
#pragma unroll
    for (int i = 0; i < 16; ++i) {
        int row = rr + i * 4;
        dst[(long)(c0 + row) * R + r0 + col] = f2bf(tile[col][row]);
    }
}

// beff[g][h] = sum_k b1[g][k]*W2[g][k][h] + b2[g][h]
__global__ void hq_beff(const unsigned short* __restrict__ w2t, const float* __restrict__ b1,
                        const float* __restrict__ b2, float* __restrict__ beff) {
    int g = blockIdx.y;
    int h = blockIdx.x * 256 + threadIdx.x;
    const unsigned short* row = w2t + ((long)(g * 1024 + h)) * 1024;
    float s = 0.f;
    for (int k = 0; k < 1024; k += 8) {
        bf16x8 v = *reinterpret_cast<const bf16x8*>(row + k);
#pragma unroll
        for (int j = 0; j < 8; ++j) s += bf2f((unsigned short)v[j]) * b1[g * 1024 + k + j];
    }
    beff[g * 1024 + h] = s + b2[g * 1024 + h];
}

// WeffT[g][h][d] = sum_k W2T[g][h][k] * W1[g][d][k]
__global__ void hq_weff(const unsigned short* __restrict__ w2t, const float* __restrict__ w1,
                        unsigned short* __restrict__ wefft) {
    __shared__ unsigned short atile[64][136];
    const int g = blockIdx.z;
    const int d0 = blockIdx.x * 64;
    const int h0 = blockIdx.y * 64;
    const int tid = threadIdx.x;
    const int w = tid >> 6, lane = tid & 63;
    const int fr = lane & 15, fq = lane >> 4;
    f32x4 acc[4] = {};
    const int drow = d0 + w * 16 + fr;
    const float* bsrc = w1 + ((long)g * 2048 + drow) * 1024;
    for (int kc = 0; kc < 8; ++kc) {
#pragma unroll
        for (int i = 0; i < 4; ++i) {
            int id = tid + i * 256;
            int row = id >> 4, c8 = id & 15;
            bf16x8 v = *reinterpret_cast<const bf16x8*>(
                w2t + ((long)(g * 1024 + h0 + row)) * 1024 + kc * 128 + c8 * 8);
            *reinterpret_cast<bf16x8*>(&atile[row][c8 * 8]) = v;
        }
        __syncthreads();
#pragma unroll
        for (int kk = 0; kk < 4; ++kk) {
            int kl = kk * 32 + fq * 8;
            int kg = kc * 128 + kl;
            float4 bA = *reinterpret_cast<const float4*>(bsrc + kg);
            float4 bB = *reinterpret_cast<const float4*>(bsrc + kg + 4);
            bf16x8 bfv;
            bfv[0] = (short)f2bf(bA.x); bfv[1] = (short)f2bf(bA.y);
            bfv[2] = (short)f2bf(bA.z); bfv[3] = (short)f2bf(bA.w);
            bfv[4] = (short)f2bf(bB.x); bfv[5] = (short)f2bf(bB.y);
            bfv[6] = (short)f2bf(bB.z); bfv[7] = (short)f2bf(bB.w);
#pragma unroll
            for (int mi = 0; mi < 4; ++mi) {
                bf16x8 af = *reinterpret_cast<const bf16x8*>(&atile[mi * 16 + fr][kl]);
                acc[mi] = __builtin_amdgcn_mfma_f32_16x16x32_bf16(af, bfv, acc[mi], 0, 0, 0);
            }
        }
        __syncthreads();
    }
#pragma unroll
    for (int mi = 0; mi < 4; ++mi)
#pragma unroll
        for (int r = 0; r < 4; ++r) {
            int h = h0 + mi * 16 + fq * 4 + r;
            int d = d0 + w * 16 + fr;
            wefft[((long)(g * 1024 + h)) * 2048 + d] = f2bf(acc[mi][r]);
        }
}

// inputs f32 -> bf16
__global__ void hq_xconv(const float* __restrict__ x, unsigned short* __restrict__ xbf) {
    long i = (long)blockIdx.x * 256 + threadIdx.x;
    for (; i < 4194304L; i += 524288L) {
        float4 v = reinterpret_cast<const float4*>(x)[i];
        ushort4 o;
        o.x = f2bf(v.x); o.y = f2bf(v.y); o.z = f2bf(v.z); o.w = f2bf(v.w);
        reinterpret_cast<ushort4*>(xbf)[i] = o;
    }
}

// Wide coherent hx load: 8x dwordx4 from LLC (sc0 sc1 = bypass L1+L2), one wait.
__device__ __forceinline__ void coh_load_hx(const void* pa, const void* pb, bf16x8* af) {
    asm volatile(
        "global_load_dwordx4 %0, %[a], off sc0 sc1\n\t"
        "global_load_dwordx4 %1, %[a], off offset:64 sc0 sc1\n\t"
        "global_load_dwordx4 %2, %[a], off offset:128 sc0 sc1\n\t"
        "global_load_dwordx4 %3, %[a], off offset:192 sc0 sc1\n\t"
        "global_load_dwordx4 %4, %[b], off sc0 sc1\n\t"
        "global_load_dwordx4 %5, %[b], off offset:64 sc0 sc1\n\t"
        "global_load_dwordx4 %6, %[b], off offset:128 sc0 sc1\n\t"
        "global_load_dwordx4 %7, %[b], off offset:192 sc0 sc1\n\t"
        "s_waitcnt vmcnt(0)"
        : "=&v"(af[0]), "=&v"(af[1]), "=&v"(af[2]), "=&v"(af[3]),
          "=&v"(af[4]), "=&v"(af[5]), "=&v"(af[6]), "=&v"(af[7])
        : [a] "v"(pa), [b] "v"(pb)
        : "memory");
}
// Coherent 4B flag read (MALL-direct)
__device__ __forceinline__ unsigned coh_load_flag(const unsigned* p) {
    unsigned r;
    asm volatile(
        "global_load_dword %0, %[a], off sc0 sc1\n\t"
        "s_waitcnt vmcnt(0)"
        : "=&v"(r) : [a] "v"(p) : "memory");
    return r;
}
__device__ __forceinline__ void vm_drain() {
    asm volatile("s_waitcnt vmcnt(0)" ::: "memory");
}
// LDS-only barrier: does NOT drain VMEM (in-flight global loads/stores survive).
__device__ __forceinline__ void lgkm_barrier() {
    asm volatile("s_waitcnt lgkmcnt(0)\n\ts_barrier" ::: "memory");
    __builtin_amdgcn_sched_barrier(0);
}

// Persistent sequential kernel. Per-wave producer gating + lgkm-only barriers.
// grid 256 = (bq 2) x (cb 128); block 1024 = 16 waves, wave kq owns 128-K-slice.
// kq0-7: x (prefetched across steps). kq8-15: hx; wave kq polls ONLY its 16
// producer flags (cb' = (kq-8)*16..+15), then MALL-direct hx load. Epilogue
// waves 0-3 (no HBM); waves 12-15 store outs (floats across lgkm barriers).
__global__ __launch_bounds__(1024, 4) void hq_seq(
    const unsigned short* __restrict__ xbf,     // [256][64][1024] bf16
    const unsigned short* __restrict__ wefft,   // [4][1024][2048] bf16
    const float* __restrict__ beff,             // [4][1024]
    float* __restrict__ outs,                   // [256][64][1024] f32
    float* __restrict__ hxf, float* __restrict__ cxf,
    unsigned short* __restrict__ hxbuf,         // [2][64][1024] bf16 (no init needed)
    unsigned* __restrict__ flags)               // [256] zeroed per launch
{
    __shared__ float zpart[16][2][32][16];      // 64 KB, row XOR-swizzled
    __shared__ float hvbuf[256];                // hv handoff epilogue -> waves 12-15
    __shared__ float cbuf[256];                 // creg handoff (final step only)
    const int tid = threadIdx.x;
    const int lane = tid & 63, kq = tid >> 6;
    const int fr = lane & 15, fq = lane >> 4;
    const int bid = blockIdx.x;
    const int bq = bid >> 7, cb = bid & 127;
    const int b0 = bq * 32, ho = cb * 8;
    const int k0 = kq * 128;

    // ---- preload B fragments: [nt 2][ks 4] = 32 regs/lane ----
    bf16x8 breg[2][4];
#pragma unroll
    for (int nt = 0; nt < 2; ++nt) {
        const int col = nt * 16 + fr;
        const int g = col >> 3, hl = col & 7;
        const unsigned short* wrow = wefft + ((long)(g * 1024 + ho + hl)) * 2048 + k0 + fq * 8;
#pragma unroll
        for (int s = 0; s < 4; ++s) breg[nt][s] = *(const bf16x8*)(wrow + s * 32);
    }

    const int eb = tid >> 3, ehl = tid & 7;
    float creg = 0.f;
    float be[4] = {0.f, 0.f, 0.f, 0.f};
    if (tid < 256) {
#pragma unroll
        for (int g = 0; g < 4; ++g) be[g] = beff[g * 1024 + ho + ehl];
    }

    // per-wave producer flag address (hx waves only)
    const unsigned* my_flag = flags + bq * 128 + ((kq - 8) & 7) * 16 + fr;

    bf16x8 af[8];                                 // x waves: persistent (prefetch)
    if (kq < 8) {
        const unsigned short* p0 = xbf + ((long)(b0 + fr)) * 1024 + k0 + fq * 8;
        const unsigned short* p1 = p0 + 16 * 1024;
#pragma unroll
        for (int s = 0; s < 4; ++s) {
            af[s]     = *(const bf16x8*)(p0 + s * 32);
            af[4 + s] = *(const bf16x8*)(p1 + s * 32);
        }
    }

    for (int t = 0; t < TSTEPS; ++t) {
        if (kq >= 8) {
            if (t == 0) {
#pragma unroll
                for (int i = 0; i < 8; ++i) af[i] = (bf16x8){0, 0, 0, 0, 0, 0, 0, 0};
            } else {
                // per-wave gate: wait only the 16 producers of this K-slice
                for (int g = 0; g < (1 << 16); ++g) {
                    unsigned v = coh_load_flag(my_flag);
                    if (__all(v >= (unsigned)t)) break;
                }
                const unsigned short* hx_r = hxbuf + (t & 1) * 65536;
                const char* pa = (const char*)(hx_r + ((long)(b0 + fr)) * 1024 + (k0 - 1024) + fq * 8);
                const char* pb = pa + 32768;      // +16 rows * 2048 B
                coh_load_hx(pa, pb, af);
            }
        }

        f32x4 acc[2][2] = {};
#pragma unroll
        for (int s = 0; s < 4; ++s)
#pragma unroll
            for (int mt = 0; mt < 2; ++mt)
#pragma unroll
                for (int nt = 0; nt < 2; ++nt)
                    acc[mt][nt] = __builtin_amdgcn_mfma_f32_16x16x32_bf16(
                        af[mt * 4 + s], breg[nt][s], acc[mt][nt], 0, 0, 0);

#pragma unroll
        for (int mt = 0; mt < 2; ++mt)
#pragma unroll
            for (int nt = 0; nt < 2; ++nt) {
                const int col = nt * 16 + fr;
                const int prow = (fq * 4) ^ ((col & 3) << 2);
                *(f32x4*)&zpart[kq][mt][col][prow] = acc[mt][nt];
            }
        lgkm_barrier();                           // B1: zpart ready (no VMEM drain)

        if (tid < 256) {
            const int emt = eb >> 4, erow = eb & 15;
            float z[4];
#pragma unroll
            for (int g = 0; g < 4; ++g) {
                const int col = g * 8 + ehl;
                const int pr = erow ^ ((col & 3) << 2);
                float s = be[g];
#pragma unroll
                for (int q = 0; q < 16; ++q) s += zpart[q][emt][col][pr];
                z[g] = s;
            }
            float fg = 1.f / (1.f + __expf(-z[0]));
            float ig = 1.f / (1.f + __expf(-z[1]));
            float gg = 2.f / (1.f + __expf(-2.f * z[2])) - 1.f;
            float og = 1.f / (1.f + __expf(-z[3]));
            creg = fg * creg + ig * gg;
            float hv = og * (2.f / (1.f + __expf(-2.f * creg)) - 1.f);
            const int b = b0 + eb, h = ho + ehl;
            hvbuf[tid] = hv;
            if (t == TSTEPS - 1) cbuf[tid] = creg;

            // hx write-through: pack even/odd h pair into one u32 agent store
            unsigned hb = (unsigned)f2bf(hv);
            unsigned ob = (unsigned)__shfl_xor((int)hb, 1);
            if ((tid & 1) == 0) {
                unsigned pack = (hb & 0xFFFFu) | (ob << 16);
                unsigned* hx_w = (unsigned*)(hxbuf + ((t + 1) & 1) * 65536 + b * 1024 + h);
                __hip_atomic_store(hx_w, pack, __ATOMIC_RELAXED, __HIP_MEMORY_SCOPE_AGENT);
            }
            vm_drain();                           // waits ONLY the hx MALL stores
        }
        lgkm_barrier();                           // B2: drains joined + hvbuf visible
        if (tid == 0)
            __hip_atomic_store(flags + bid, (unsigned)(t + 1), __ATOMIC_RELAXED,
                               __HIP_MEMORY_SCOPE_AGENT);
        // x prefetch for t+1 (rides across barriers & poll windows)
        if (kq < 8 && t + 1 < TSTEPS) {
            const unsigned short* p0 = xbf + ((long)((t + 1) * 64 + b0 + fr)) * 1024 + k0 + fq * 8;
            const unsigned short* p1 = p0 + 16 * 1024;
#pragma unroll
            for (int s = 0; s < 4; ++s) {
                af[s]     = *(const bf16x8*)(p0 + s * 32);
                af[4 + s] = *(const bf16x8*)(p1 + s * 32);
            }
        }
        // HBM stores by waves 12-15 (in flight across lgkm barriers; ack waited
        // only by their own next hx-load vmcnt, which hits L2-acked stores)
        if (tid >= 768) {
            const int et = tid - 768;
            const int b = b0 + (et >> 3), h = ho + (et & 7);
            float hv = hvbuf[et];
            outs[((long)(t * 64 + b)) * 1024 + h] = hv;
            if (t == TSTEPS - 1) { hxf[b * 1024 + h] = hv; cxf[b * 1024 + h] = cbuf[et]; }
        }
    }
}

extern "C" void kernel_launch(void* const* d_in, const int* in_sizes, int n_in,
                              void* d_out, int out_size, void* d_ws, size_t ws_size,
                              hipStream_t stream) {
    (void)in_sizes; (void)n_in; (void)out_size;
    const float* x  = (const float*)d_in[0];
    const float* W1 = (const float*)d_in[1];
    const float* b1 = (const float*)d_in[2];
    const float* W2 = (const float*)d_in[3];
    const float* b2 = (const float*)d_in[4];
    float* outs = (float*)d_out;
    float* hxf = outs + 16777216L;
    float* cxf = hxf + 65536;

    // ws layout (bytes)
    const size_t off_wefft = 0;          // 16,777,216  WeffT bf16 [4][1024][2048]
    const size_t off_xbf   = 16777216;   // 33,554,432  xbf bf16 (w2t aliased at head)
    const size_t off_w2t   = off_xbf;    //  8,388,608  consumed before xconv overwrites
    const size_t off_hx    = 50331648;   //    262,144  hx ping-pong [2][64][1024] bf16
    const size_t off_beff  = 50593792;   //     16,384
    const size_t off_flags = 50610176;   //      1,024  flags[256]
    const size_t need      = 50611200;
    if (ws_size < need) { hq_marker<<<1, 1, 0, stream>>>((float*)d_out); return; }

    char* ws = (char*)d_ws;
    unsigned short* wefft = (unsigned short*)(ws + off_wefft);
    unsigned short* xbf   = (unsigned short*)(ws + off_xbf);
    unsigned short* w2t   = (unsigned short*)(ws + off_w2t);
    unsigned short* hxbuf = (unsigned short*)(ws + off_hx);
    float* beff = (float*)(ws + off_beff);
    unsigned* flags = (unsigned*)(ws + off_flags);

    hipMemsetAsync(ws + off_flags, 0, 1024, stream);   // flags = 0 (every replay)
    hq_transpose<<<dim3(16, 16, 4), 256, 0, stream>>>(W2, w2t);
    hq_beff<<<dim3(4, 4), 256, 0, stream>>>(w2t, b1, b2, beff);
    hq_weff<<<dim3(32, 16, 4), 256, 0, stream>>>(w2t, W1, wefft);
    hq_xconv<<<2048, 256, 0, stream>>>(x, xbf);

    const unsigned short* xbf_c = xbf;
    const unsigned short* wefft_c = wefft;
    const float* beff_c = beff;
    void* args[] = { (void*)&xbf_c, (void*)&wefft_c, (void*)&beff_c,
                     (void*)&outs, (void*)&hxf, (void*)&cxf,
                     (void*)&hxbuf, (void*)&flags };
    hipError_t ce = hipLaunchCooperativeKernel((const void*)hq_seq, dim3(NBLK), dim3(1024),
                                               args, 0, stream);
    if (ce != hipSuccess) {
        // 1 block/CU by resource limits; 256 blocks <= 256 CUs -> co-resident anyway
        hq_seq<<<NBLK, 1024, 0, stream>>>(xbf, wefft, beff, outs, hxf, cxf, hxbuf, flags);
    }
}